// Round 1
// baseline (414.529 us; speedup 1.0000x reference)
//
#include <hip/hip_runtime.h>
#include <math.h>

#define S 2048
#define B 16
#define H 512
#define L 4096
#define SMAX 16
#define LAB 256
#define V 32000
#define NCH 250          // V / 128 vocab chunks
#define LOG2E 1.44269504f

typedef __attribute__((ext_vector_type(8))) short short8;
typedef __attribute__((ext_vector_type(4))) float float4v;

__device__ inline ushort f2bf(float x) {
  union { float f; unsigned u; } c; c.f = x;
  unsigned r = c.u + 0x7fffu + ((c.u >> 16) & 1u);
  return (ushort)(r >> 16);
}
__device__ inline float bf2f(ushort h) {
  union { unsigned u; float f; } c; c.u = ((unsigned)h) << 16;
  return c.f;
}

// ---------------------------------------------------------------- kernel A
// span gather -> spanb bf16 [L][1536] = concat(left, mean, right)
__global__ __launch_bounds__(256) void spanb_kernel(
    const float* __restrict__ hidden, const int* __restrict__ begins,
    const int* __restrict__ ends, const int* __restrict__ bids,
    ushort* __restrict__ spanb) {
  int sub = threadIdx.x >> 7, t = threadIdx.x & 127;
  int l = blockIdx.x * 2 + sub;
  int b = bids[l], s0 = begins[l], s1 = ends[l];
  const float4* hidv = (const float4*)hidden;
  float4 lf = hidv[((size_t)(s0 - 1) * B + b) * 128 + t];
  float4 rf = hidv[((size_t)s1 * B + b) * 128 + t];
  float4 m = make_float4(0.f, 0.f, 0.f, 0.f);
  int len = s1 - s0;
  for (int j = 0; j < len; ++j) {
    float4 g = hidv[((size_t)(s0 + j) * B + b) * 128 + t];
    m.x += g.x; m.y += g.y; m.z += g.z; m.w += g.w;
  }
  float inv = 1.0f / (float)len;
  ushort* sp = spanb + (size_t)l * 1536;
  ushort4 u;
  u.x = f2bf(lf.x); u.y = f2bf(lf.y); u.z = f2bf(lf.z); u.w = f2bf(lf.w);
  *(ushort4*)&sp[t * 4] = u;
  u.x = f2bf(m.x * inv); u.y = f2bf(m.y * inv);
  u.z = f2bf(m.z * inv); u.w = f2bf(m.w * inv);
  *(ushort4*)&sp[512 + t * 4] = u;
  u.x = f2bf(rf.x); u.y = f2bf(rf.y); u.z = f2bf(rf.z); u.w = f2bf(rf.w);
  *(ushort4*)&sp[1024 + t * 4] = u;
}

// ---------------------------------------------------------------- kernel B
// generic transpose+cast: src[K][N] f32 -> dst[N][K] bf16
__global__ __launch_bounds__(256) void tcast_kernel(
    const float* __restrict__ src, ushort* __restrict__ dst, int K, int N) {
  __shared__ ushort tile[64 * 72];
  int t = threadIdx.x;
  int n0 = blockIdx.x * 64;
  int k0 = blockIdx.y * 64;
  #pragma unroll
  for (int p = 0; p < 16; ++p) {
    int k = p * 4 + (t >> 6);
    int n = t & 63;
    tile[n * 72 + k] = f2bf(src[(size_t)(k0 + k) * N + n0 + n]);
  }
  __syncthreads();
  #pragma unroll
  for (int p = 0; p < 2; ++p) {
    int idx = p * 256 + t;
    int n = idx >> 3, c = idx & 7;
    *(uint4*)&dst[(size_t)(n0 + n) * K + k0 + c * 8] =
        *(const uint4*)&tile[n * 72 + c * 8];
  }
}

// ---------------------------------------------------------------- kernel C
// MFMA MLP: featb = bf16( sigmoid(spanb@W1+b1) @ W2 + b2 )
#define FST 72
__global__ __launch_bounds__(256, 2) void feat_mfma_kernel(
    const ushort* __restrict__ spanb, const ushort* __restrict__ W1b,
    const float* __restrict__ b1, const ushort* __restrict__ W2b,
    const float* __restrict__ b2, ushort* __restrict__ featb) {
  __shared__ ushort As[32 * FST];
  __shared__ ushort Bs[256 * FST];
  __shared__ ushort Hs[32 * 264];
  int tid = threadIdx.x;
  int w = tid >> 6, lane = tid & 63;
  int lr = lane & 15, lq = lane >> 4;
  int l0 = blockIdx.x * 32;

  float4v acc[2][4];
  float4v zero = {0.f, 0.f, 0.f, 0.f};
  #pragma unroll
  for (int mt = 0; mt < 2; ++mt)
    #pragma unroll
    for (int nt = 0; nt < 4; ++nt) acc[mt][nt] = zero;

  for (int s = 0; s < 24; ++s) {
    int ks = s * 64;
    __syncthreads();
    {
      int r = tid >> 3, c = tid & 7;
      *(uint4*)&As[r * FST + c * 8] =
          *(const uint4*)&spanb[(size_t)(l0 + r) * 1536 + ks + c * 8];
    }
    #pragma unroll
    for (int p = 0; p < 8; ++p) {
      int idx = p * 256 + tid;
      int r = idx >> 3, c = idx & 7;
      *(uint4*)&Bs[r * FST + c * 8] =
          *(const uint4*)&W1b[(size_t)r * 1536 + ks + c * 8];
    }
    __syncthreads();
    #pragma unroll
    for (int kk = 0; kk < 2; ++kk) {
      short8 af[2], bf[4];
      #pragma unroll
      for (int mt = 0; mt < 2; ++mt)
        af[mt] = *(const short8*)&As[(mt * 16 + lr) * FST + kk * 32 + lq * 8];
      #pragma unroll
      for (int nt = 0; nt < 4; ++nt)
        bf[nt] = *(const short8*)
            &Bs[(w * 64 + nt * 16 + lr) * FST + kk * 32 + lq * 8];
      #pragma unroll
      for (int mt = 0; mt < 2; ++mt)
        #pragma unroll
        for (int nt = 0; nt < 4; ++nt)
          acc[mt][nt] = __builtin_amdgcn_mfma_f32_16x16x32_bf16(
              af[mt], bf[nt], acc[mt][nt], 0, 0, 0);
    }
  }

  {
    float b1v[4];
    #pragma unroll
    for (int nt = 0; nt < 4; ++nt) b1v[nt] = b1[w * 64 + nt * 16 + lr];
    #pragma unroll
    for (int mt = 0; mt < 2; ++mt)
      #pragma unroll
      for (int nt = 0; nt < 4; ++nt)
        #pragma unroll
        for (int r = 0; r < 4; ++r) {
          int row = mt * 16 + lq * 4 + r;
          int col = w * 64 + nt * 16 + lr;
          float h = 1.0f / (1.0f + __expf(-(acc[mt][nt][r] + b1v[nt])));
          Hs[row * 264 + col] = f2bf(h);
        }
  }

  float4v acc2[2][4];
  #pragma unroll
  for (int mt = 0; mt < 2; ++mt)
    #pragma unroll
    for (int nt = 0; nt < 4; ++nt) acc2[mt][nt] = zero;

  for (int s = 0; s < 4; ++s) {
    int ks = s * 64;
    __syncthreads();
    #pragma unroll
    for (int p = 0; p < 8; ++p) {
      int idx = p * 256 + tid;
      int r = idx >> 3, c = idx & 7;
      *(uint4*)&Bs[r * FST + c * 8] =
          *(const uint4*)&W2b[(size_t)r * 256 + ks + c * 8];
    }
    __syncthreads();
    #pragma unroll
    for (int kk = 0; kk < 2; ++kk) {
      short8 af[2], bf[4];
      #pragma unroll
      for (int mt = 0; mt < 2; ++mt)
        af[mt] = *(const short8*)
            &Hs[(mt * 16 + lr) * 264 + ks + kk * 32 + lq * 8];
      #pragma unroll
      for (int nt = 0; nt < 4; ++nt)
        bf[nt] = *(const short8*)
            &Bs[(w * 64 + nt * 16 + lr) * FST + kk * 32 + lq * 8];
      #pragma unroll
      for (int mt = 0; mt < 2; ++mt)
        #pragma unroll
        for (int nt = 0; nt < 4; ++nt)
          acc2[mt][nt] = __builtin_amdgcn_mfma_f32_16x16x32_bf16(
              af[mt], bf[nt], acc2[mt][nt], 0, 0, 0);
    }
  }

  {
    float b2v[4];
    #pragma unroll
    for (int nt = 0; nt < 4; ++nt) b2v[nt] = b2[w * 64 + nt * 16 + lr];
    #pragma unroll
    for (int mt = 0; mt < 2; ++mt)
      #pragma unroll
      for (int nt = 0; nt < 4; ++nt)
        #pragma unroll
        for (int r = 0; r < 4; ++r) {
          int row = mt * 16 + lq * 4 + r;
          int col = w * 64 + nt * 16 + lr;
          featb[(size_t)(l0 + row) * 256 + col] =
              f2bf(acc2[mt][nt][r] + b2v[nt]);
        }
  }
}

// ---------------------------------------------------------------- kernel D
// Persistent-chunk logits + sumexp partials.
// grid: (2 label halves, 250 vocab chunks) = 500 blocks (~2/CU, one round).
// Each block stages its 128-row Wob chunk to LDS ONCE (64 KB), then loops
// over 8 label tiles of 256 with NO barriers (LDS read-only after stage).
// MFMA work per stage is 8x the old version; Wob HBM traffic drops 16x->2x.
// A-frags direct from global (featb L2-resident), double-buffered across K;
// next tile's first A-frag prefetched under the exp2/shuffle epilogue.
#define BST2 264
__global__ __launch_bounds__(256, 2) void logits2_kernel(
    const ushort* __restrict__ featb, const ushort* __restrict__ Wob,
    const float* __restrict__ bo, float* __restrict__ pz) {
  __shared__ ushort Blds[128 * BST2];    // 66 KB
  int tid = threadIdx.x;
  int v0 = blockIdx.y * 128;
  int w = tid >> 6, lane = tid & 63;
  int lr = lane & 15, lq = lane >> 4;

  // stage B: 128 rows x 256 ushorts = 4096 uint4, coalesced
  {
    const uint4* src = (const uint4*)(Wob + (size_t)v0 * 256);
    #pragma unroll
    for (int p = 0; p < 16; ++p) {
      int idx = p * 256 + tid;
      int r = idx >> 5, c = idx & 31;
      *(uint4*)&Blds[r * BST2 + c * 8] = src[idx];
    }
  }

  float bov[8];
  #pragma unroll
  for (int nt = 0; nt < 8; ++nt)
    bov[nt] = bo[v0 + nt * 16 + lr] * LOG2E;

  __syncthreads();                       // the only barrier

  int ch = blockIdx.y;
  int lhalf = blockIdx.x * 2048;
  // wave's A base: row (lhalf + w*64 + lr), col lq*8.
  // offsets in short8 units: tile(+256 rows)=8192, mt(+16 rows)=512, k-step=4.
  const short8* aptr = (const short8*)(featb +
      (size_t)(lhalf + w * 64 + lr) * 256 + lq * 8);

  short8 af0[4];
  #pragma unroll
  for (int mt = 0; mt < 4; ++mt) af0[mt] = aptr[mt * 512];

  for (int lt = 0; lt < 8; ++lt) {
    const size_t tb = (size_t)lt * 8192;

    float4v acc[4][8];
    float4v zero = {0.f, 0.f, 0.f, 0.f};
    #pragma unroll
    for (int mt = 0; mt < 4; ++mt)
      #pragma unroll
      for (int nt = 0; nt < 8; ++nt) acc[mt][nt] = zero;

    short8 af[2][4];
    #pragma unroll
    for (int mt = 0; mt < 4; ++mt) af[0][mt] = af0[mt];

    #pragma unroll
    for (int k = 0; k < 8; ++k) {        // K = 8 steps of 32
      int cur = k & 1, nxt = cur ^ 1;
      if (k < 7) {
        #pragma unroll
        for (int mt = 0; mt < 4; ++mt)
          af[nxt][mt] = aptr[tb + mt * 512 + (k + 1) * 4];
      }
      short8 bf[8];
      #pragma unroll
      for (int nt = 0; nt < 8; ++nt)
        bf[nt] = *(const short8*)&Blds[(nt * 16 + lr) * BST2 + k * 32 + lq * 8];
      #pragma unroll
      for (int mt = 0; mt < 4; ++mt)
        #pragma unroll
        for (int nt = 0; nt < 8; ++nt)
          acc[mt][nt] = __builtin_amdgcn_mfma_f32_16x16x32_bf16(
              af[cur][mt], bf[nt], acc[mt][nt], 0, 0, 0);
    }

    // prefetch next tile's first A-frags; latency hidden under epilogue
    if (lt < 7) {
      #pragma unroll
      for (int mt = 0; mt < 4; ++mt)
        af0[mt] = aptr[tb + 8192 + mt * 512];
    }

    // epilogue: z[row] = sum_cols exp(logit + bo), no max (logits bounded)
    float z[4][4];
    #pragma unroll
    for (int mt = 0; mt < 4; ++mt)
      #pragma unroll
      for (int r = 0; r < 4; ++r) z[mt][r] = 0.f;
    #pragma unroll
    for (int mt = 0; mt < 4; ++mt)
      #pragma unroll
      for (int nt = 0; nt < 8; ++nt)
        #pragma unroll
        for (int r = 0; r < 4; ++r)
          z[mt][r] += exp2f(fmaf(acc[mt][nt][r], LOG2E, bov[nt]));
    #pragma unroll
    for (int mt = 0; mt < 4; ++mt)
      #pragma unroll
      for (int r = 0; r < 4; ++r) {
        #pragma unroll
        for (int off = 1; off < 16; off <<= 1)
          z[mt][r] += __shfl_xor(z[mt][r], off);
      }
    if (lr == 0) {
      int l0 = lhalf + lt * 256;
      #pragma unroll
      for (int mt = 0; mt < 4; ++mt)
        #pragma unroll
        for (int r = 0; r < 4; ++r)
          pz[(size_t)ch * L + l0 + w * 64 + mt * 16 + lq * 4 + r] = z[mt][r];
    }
  }
}

// ---------------------------------------------------------------- kernel E
// Exact tag logit: tagl[l] = featb[l]·Wob[tags[l]] + bo[tags[l]]
__global__ __launch_bounds__(256) void tag_kernel(
    const ushort* __restrict__ featb, const ushort* __restrict__ Wob,
    const float* __restrict__ bo, const int* __restrict__ tags,
    float* __restrict__ tagl) {
  int l = blockIdx.x * 4 + (threadIdx.x >> 6);
  int lane = threadIdx.x & 63;
  int tg = tags[l];
  ushort4 fa = *(const ushort4*)&featb[(size_t)l * 256 + lane * 4];
  ushort4 wa = *(const ushort4*)&Wob[(size_t)tg * 256 + lane * 4];
  float s = bf2f(fa.x) * bf2f(wa.x) + bf2f(fa.y) * bf2f(wa.y) +
            bf2f(fa.z) * bf2f(wa.z) + bf2f(fa.w) * bf2f(wa.w);
  #pragma unroll
  for (int off = 1; off < 64; off <<= 1) s += __shfl_xor(s, off);
  if (lane == 0) tagl[l] = s + bo[tg];
}

// ---------------------------------------------------------------- kernel F
__global__ __launch_bounds__(256) void reduce_kernel(
    const float* __restrict__ pz, const float* __restrict__ tagl,
    float* __restrict__ out) {
  int l = blockIdx.x * 256 + threadIdx.x;
  float z = 0.f;
  for (int c = 0; c < NCH; ++c) z += pz[(size_t)c * L + l];
  float per = logf(z) - tagl[l];
  float v = per * (1.0f / (4096.0f + 1e-5f));
  #pragma unroll
  for (int off = 1; off < 64; off <<= 1) v += __shfl_xor(v, off);
  __shared__ float wsum[4];
  if ((threadIdx.x & 63) == 0) wsum[threadIdx.x >> 6] = v;
  __syncthreads();
  if (threadIdx.x == 0)
    atomicAdd(out, wsum[0] + wsum[1] + wsum[2] + wsum[3]);
}

// ---------------------------------------------------------------- launch
extern "C" void kernel_launch(void* const* d_in, const int* in_sizes, int n_in,
                              void* d_out, int out_size, void* d_ws,
                              size_t ws_size, hipStream_t stream) {
  const float* hidden = (const float*)d_in[0];
  const int* begins = (const int*)d_in[1];
  const int* ends = (const int*)d_in[2];
  const int* bids = (const int*)d_in[3];
  const int* tags = (const int*)d_in[4];
  const float* W1 = (const float*)d_in[5];
  const float* b1 = (const float*)d_in[6];
  const float* W2 = (const float*)d_in[7];
  const float* b2 = (const float*)d_in[8];
  const float* Wo = (const float*)d_in[9];
  const float* bo = (const float*)d_in[10];
  float* out = (float*)d_out;

  ushort* featb = (ushort*)d_ws;                       // L*256
  ushort* Wob = featb + (size_t)L * 256;               // V*256
  ushort* spanb = Wob + (size_t)V * 256;               // L*1536
  ushort* W1b = spanb + (size_t)L * 1536;              // 256*1536
  ushort* W2b = W1b + (size_t)256 * 1536;              // 256*256
  float* pz = (float*)(W2b + (size_t)256 * 256);       // NCH*L
  float* tagl = pz + (size_t)NCH * L;                  // L

  hipMemsetAsync(d_out, 0, sizeof(float), stream);
  spanb_kernel<<<L / 2, 256, 0, stream>>>(hidden, begins, ends, bids, spanb);
  tcast_kernel<<<dim3(4, 24), 256, 0, stream>>>(W1, W1b, 1536, LAB);
  tcast_kernel<<<dim3(4, 4), 256, 0, stream>>>(W2, W2b, LAB, LAB);
  tcast_kernel<<<dim3(500, 4), 256, 0, stream>>>(Wo, Wob, LAB, V);
  feat_mfma_kernel<<<128, 256, 0, stream>>>(spanb, W1b, b1, W2b, b2, featb);
  logits2_kernel<<<dim3(2, NCH), 256, 0, stream>>>(featb, Wob, bo, pz);
  tag_kernel<<<L / 4, 256, 0, stream>>>(featb, Wob, bo, tags, tagl);
  reduce_kernel<<<L / 256, 256, 0, stream>>>(pz, tagl, out);
}

// Round 2
// 344.426 us; speedup vs baseline: 1.2035x; 1.2035x over previous
//
#include <hip/hip_runtime.h>
#include <math.h>

#define S 2048
#define B 16
#define H 512
#define L 4096
#define SMAX 16
#define LAB 256
#define V 32000
#define NCH2 500         // V / 64 vocab chunks
#define LOG2E 1.44269504f

typedef __attribute__((ext_vector_type(8))) short short8;
typedef __attribute__((ext_vector_type(4))) float float4v;

__device__ inline ushort f2bf(float x) {
  union { float f; unsigned u; } c; c.f = x;
  unsigned r = c.u + 0x7fffu + ((c.u >> 16) & 1u);
  return (ushort)(r >> 16);
}
__device__ inline float bf2f(ushort h) {
  union { unsigned u; float f; } c; c.u = ((unsigned)h) << 16;
  return c.f;
}

// ---------------------------------------------------------------- kernel A
// span gather -> spanb bf16 [L][1536] = concat(left, mean, right)
__global__ __launch_bounds__(256) void spanb_kernel(
    const float* __restrict__ hidden, const int* __restrict__ begins,
    const int* __restrict__ ends, const int* __restrict__ bids,
    ushort* __restrict__ spanb) {
  int sub = threadIdx.x >> 7, t = threadIdx.x & 127;
  int l = blockIdx.x * 2 + sub;
  int b = bids[l], s0 = begins[l], s1 = ends[l];
  const float4* hidv = (const float4*)hidden;
  float4 lf = hidv[((size_t)(s0 - 1) * B + b) * 128 + t];
  float4 rf = hidv[((size_t)s1 * B + b) * 128 + t];
  float4 m = make_float4(0.f, 0.f, 0.f, 0.f);
  int len = s1 - s0;
  for (int j = 0; j < len; ++j) {
    float4 g = hidv[((size_t)(s0 + j) * B + b) * 128 + t];
    m.x += g.x; m.y += g.y; m.z += g.z; m.w += g.w;
  }
  float inv = 1.0f / (float)len;
  ushort* sp = spanb + (size_t)l * 1536;
  ushort4 u;
  u.x = f2bf(lf.x); u.y = f2bf(lf.y); u.z = f2bf(lf.z); u.w = f2bf(lf.w);
  *(ushort4*)&sp[t * 4] = u;
  u.x = f2bf(m.x * inv); u.y = f2bf(m.y * inv);
  u.z = f2bf(m.z * inv); u.w = f2bf(m.w * inv);
  *(ushort4*)&sp[512 + t * 4] = u;
  u.x = f2bf(rf.x); u.y = f2bf(rf.y); u.z = f2bf(rf.z); u.w = f2bf(rf.w);
  *(ushort4*)&sp[1024 + t * 4] = u;
}

// ---------------------------------------------------------------- kernel B
// generic transpose+cast: src[K][N] f32 -> dst[N][K] bf16
__global__ __launch_bounds__(256) void tcast_kernel(
    const float* __restrict__ src, ushort* __restrict__ dst, int K, int N) {
  __shared__ ushort tile[64 * 72];
  int t = threadIdx.x;
  int n0 = blockIdx.x * 64;
  int k0 = blockIdx.y * 64;
  #pragma unroll
  for (int p = 0; p < 16; ++p) {
    int k = p * 4 + (t >> 6);
    int n = t & 63;
    tile[n * 72 + k] = f2bf(src[(size_t)(k0 + k) * N + n0 + n]);
  }
  __syncthreads();
  #pragma unroll
  for (int p = 0; p < 2; ++p) {
    int idx = p * 256 + t;
    int n = idx >> 3, c = idx & 7;
    *(uint4*)&dst[(size_t)(n0 + n) * K + k0 + c * 8] =
        *(const uint4*)&tile[n * 72 + c * 8];
  }
}

// ---------------------------------------------------------------- kernel C
// MFMA MLP: featb = bf16( sigmoid(spanb@W1+b1) @ W2 + b2 )
#define FST 72
__global__ __launch_bounds__(256, 2) void feat_mfma_kernel(
    const ushort* __restrict__ spanb, const ushort* __restrict__ W1b,
    const float* __restrict__ b1, const ushort* __restrict__ W2b,
    const float* __restrict__ b2, ushort* __restrict__ featb) {
  __shared__ ushort As[32 * FST];
  __shared__ ushort Bs[256 * FST];
  __shared__ ushort Hs[32 * 264];
  int tid = threadIdx.x;
  int w = tid >> 6, lane = tid & 63;
  int lr = lane & 15, lq = lane >> 4;
  int l0 = blockIdx.x * 32;

  float4v acc[2][4];
  float4v zero = {0.f, 0.f, 0.f, 0.f};
  #pragma unroll
  for (int mt = 0; mt < 2; ++mt)
    #pragma unroll
    for (int nt = 0; nt < 4; ++nt) acc[mt][nt] = zero;

  for (int s = 0; s < 24; ++s) {
    int ks = s * 64;
    __syncthreads();
    {
      int r = tid >> 3, c = tid & 7;
      *(uint4*)&As[r * FST + c * 8] =
          *(const uint4*)&spanb[(size_t)(l0 + r) * 1536 + ks + c * 8];
    }
    #pragma unroll
    for (int p = 0; p < 8; ++p) {
      int idx = p * 256 + tid;
      int r = idx >> 3, c = idx & 7;
      *(uint4*)&Bs[r * FST + c * 8] =
          *(const uint4*)&W1b[(size_t)r * 1536 + ks + c * 8];
    }
    __syncthreads();
    #pragma unroll
    for (int kk = 0; kk < 2; ++kk) {
      short8 af[2], bf[4];
      #pragma unroll
      for (int mt = 0; mt < 2; ++mt)
        af[mt] = *(const short8*)&As[(mt * 16 + lr) * FST + kk * 32 + lq * 8];
      #pragma unroll
      for (int nt = 0; nt < 4; ++nt)
        bf[nt] = *(const short8*)
            &Bs[(w * 64 + nt * 16 + lr) * FST + kk * 32 + lq * 8];
      #pragma unroll
      for (int mt = 0; mt < 2; ++mt)
        #pragma unroll
        for (int nt = 0; nt < 4; ++nt)
          acc[mt][nt] = __builtin_amdgcn_mfma_f32_16x16x32_bf16(
              af[mt], bf[nt], acc[mt][nt], 0, 0, 0);
    }
  }

  {
    float b1v[4];
    #pragma unroll
    for (int nt = 0; nt < 4; ++nt) b1v[nt] = b1[w * 64 + nt * 16 + lr];
    #pragma unroll
    for (int mt = 0; mt < 2; ++mt)
      #pragma unroll
      for (int nt = 0; nt < 4; ++nt)
        #pragma unroll
        for (int r = 0; r < 4; ++r) {
          int row = mt * 16 + lq * 4 + r;
          int col = w * 64 + nt * 16 + lr;
          float h = 1.0f / (1.0f + __expf(-(acc[mt][nt][r] + b1v[nt])));
          Hs[row * 264 + col] = f2bf(h);
        }
  }

  float4v acc2[2][4];
  #pragma unroll
  for (int mt = 0; mt < 2; ++mt)
    #pragma unroll
    for (int nt = 0; nt < 4; ++nt) acc2[mt][nt] = zero;

  for (int s = 0; s < 4; ++s) {
    int ks = s * 64;
    __syncthreads();
    #pragma unroll
    for (int p = 0; p < 8; ++p) {
      int idx = p * 256 + tid;
      int r = idx >> 3, c = idx & 7;
      *(uint4*)&Bs[r * FST + c * 8] =
          *(const uint4*)&W2b[(size_t)r * 256 + ks + c * 8];
    }
    __syncthreads();
    #pragma unroll
    for (int kk = 0; kk < 2; ++kk) {
      short8 af[2], bf[4];
      #pragma unroll
      for (int mt = 0; mt < 2; ++mt)
        af[mt] = *(const short8*)
            &Hs[(mt * 16 + lr) * 264 + ks + kk * 32 + lq * 8];
      #pragma unroll
      for (int nt = 0; nt < 4; ++nt)
        bf[nt] = *(const short8*)
            &Bs[(w * 64 + nt * 16 + lr) * FST + kk * 32 + lq * 8];
      #pragma unroll
      for (int mt = 0; mt < 2; ++mt)
        #pragma unroll
        for (int nt = 0; nt < 4; ++nt)
          acc2[mt][nt] = __builtin_amdgcn_mfma_f32_16x16x32_bf16(
              af[mt], bf[nt], acc2[mt][nt], 0, 0, 0);
    }
  }

  {
    float b2v[4];
    #pragma unroll
    for (int nt = 0; nt < 4; ++nt) b2v[nt] = b2[w * 64 + nt * 16 + lr];
    #pragma unroll
    for (int mt = 0; mt < 2; ++mt)
      #pragma unroll
      for (int nt = 0; nt < 4; ++nt)
        #pragma unroll
        for (int r = 0; r < 4; ++r) {
          int row = mt * 16 + lq * 4 + r;
          int col = w * 64 + nt * 16 + lr;
          featb[(size_t)(l0 + row) * 256 + col] =
              f2bf(acc2[mt][nt][r] + b2v[nt]);
        }
  }
}

// ---------------------------------------------------------------- kernel D
// Round-0 locality structure (x-fastest: 16 label-blocks per chunk
// co-scheduled -> featb + active Wob window stay L2-hot), but:
//  - chunk shrunk 128->64 vocab rows: LDS 33 KB -> 4 blocks/CU, 16 waves/CU
//    (round-0 was 2 blocks/CU, Occupancy 20%, MfmaUtil 21% = latency-bound)
//  - pz stores packed as float4: 4 active lanes x 16B = full 64B line per
//    instruction (fixes the 33x WRITE_SIZE amplification: 144 MB for 4 MB pz)
#define BST2 264
__global__ __launch_bounds__(256, 4) void logits2_kernel(
    const ushort* __restrict__ featb, const ushort* __restrict__ Wob,
    const float* __restrict__ bo, float* __restrict__ pz) {
  __shared__ ushort Blds[64 * BST2];     // 33 KB
  int tid = threadIdx.x;
  int l0 = blockIdx.x * 256;
  int v0 = blockIdx.y * 64;
  int w = tid >> 6, lane = tid & 63;
  int lr = lane & 15, lq = lane >> 4;

  // stage B: 64 rows x 256 ushorts = 2048 uint4, coalesced
  {
    const uint4* src = (const uint4*)(Wob + (size_t)v0 * 256);
    #pragma unroll
    for (int p = 0; p < 8; ++p) {
      int idx = p * 256 + tid;
      int r = idx >> 5, c = idx & 31;
      *(uint4*)&Blds[r * BST2 + c * 8] = src[idx];
    }
  }
  __syncthreads();                       // the only barrier

  // per-mt global A pointers (row-fragment base for this lane)
  // offsets in short8 (16B) units: row stride = 32, k-step (32 ushorts) = 4
  const short8* aptr[4];
  #pragma unroll
  for (int mt = 0; mt < 4; ++mt)
    aptr[mt] = (const short8*)(featb +
        (size_t)(l0 + w * 64 + mt * 16 + lr) * 256 + lq * 8);

  float4v acc[4][4];
  float4v zero = {0.f, 0.f, 0.f, 0.f};
  #pragma unroll
  for (int mt = 0; mt < 4; ++mt)
    #pragma unroll
    for (int nt = 0; nt < 4; ++nt) acc[mt][nt] = zero;

  short8 af[2][4];
  #pragma unroll
  for (int mt = 0; mt < 4; ++mt) af[0][mt] = aptr[mt][0];

  #pragma unroll
  for (int k = 0; k < 8; ++k) {          // K = 8 steps of 32
    int cur = k & 1, nxt = cur ^ 1;
    if (k < 7) {
      #pragma unroll
      for (int mt = 0; mt < 4; ++mt)
        af[nxt][mt] = aptr[mt][(k + 1) * 4];
    }
    short8 bf[4];
    #pragma unroll
    for (int nt = 0; nt < 4; ++nt)
      bf[nt] = *(const short8*)&Blds[(nt * 16 + lr) * BST2 + k * 32 + lq * 8];
    #pragma unroll
    for (int mt = 0; mt < 4; ++mt)
      #pragma unroll
      for (int nt = 0; nt < 4; ++nt)
        acc[mt][nt] = __builtin_amdgcn_mfma_f32_16x16x32_bf16(
            af[cur][mt], bf[nt], acc[mt][nt], 0, 0, 0);
  }

  // epilogue: z[row] = sum_cols exp(logit + bo), no max (logits bounded)
  float bov[4];
  #pragma unroll
  for (int nt = 0; nt < 4; ++nt)
    bov[nt] = bo[v0 + nt * 16 + lr] * LOG2E;
  float z[4][4];
  #pragma unroll
  for (int mt = 0; mt < 4; ++mt)
    #pragma unroll
    for (int r = 0; r < 4; ++r) z[mt][r] = 0.f;
  #pragma unroll
  for (int mt = 0; mt < 4; ++mt)
    #pragma unroll
    for (int nt = 0; nt < 4; ++nt)
      #pragma unroll
      for (int r = 0; r < 4; ++r)
        z[mt][r] += exp2f(fmaf(acc[mt][nt][r], LOG2E, bov[nt]));
  #pragma unroll
  for (int mt = 0; mt < 4; ++mt)
    #pragma unroll
    for (int r = 0; r < 4; ++r) {
      #pragma unroll
      for (int off = 1; off < 16; off <<= 1)
        z[mt][r] += __shfl_xor(z[mt][r], off);
    }
  if (lr == 0) {
    int ch = blockIdx.y;
    #pragma unroll
    for (int mt = 0; mt < 4; ++mt) {
      float4 v4;
      v4.x = z[mt][0]; v4.y = z[mt][1]; v4.z = z[mt][2]; v4.w = z[mt][3];
      *(float4*)&pz[(size_t)ch * L + l0 + w * 64 + mt * 16 + lq * 4] = v4;
    }
  }
}

// ---------------------------------------------------------------- kernel E
// Exact tag logit: tagl[l] = featb[l]·Wob[tags[l]] + bo[tags[l]]
__global__ __launch_bounds__(256) void tag_kernel(
    const ushort* __restrict__ featb, const ushort* __restrict__ Wob,
    const float* __restrict__ bo, const int* __restrict__ tags,
    float* __restrict__ tagl) {
  int l = blockIdx.x * 4 + (threadIdx.x >> 6);
  int lane = threadIdx.x & 63;
  int tg = tags[l];
  ushort4 fa = *(const ushort4*)&featb[(size_t)l * 256 + lane * 4];
  ushort4 wa = *(const ushort4*)&Wob[(size_t)tg * 256 + lane * 4];
  float s = bf2f(fa.x) * bf2f(wa.x) + bf2f(fa.y) * bf2f(wa.y) +
            bf2f(fa.z) * bf2f(wa.z) + bf2f(fa.w) * bf2f(wa.w);
  #pragma unroll
  for (int off = 1; off < 64; off <<= 1) s += __shfl_xor(s, off);
  if (lane == 0) tagl[l] = s + bo[tg];
}

// ---------------------------------------------------------------- kernel F
__global__ __launch_bounds__(256) void reduce_kernel(
    const float* __restrict__ pz, const float* __restrict__ tagl,
    float* __restrict__ out) {
  int l = blockIdx.x * 256 + threadIdx.x;
  float z = 0.f;
  for (int c = 0; c < NCH2; ++c) z += pz[(size_t)c * L + l];
  float per = logf(z) - tagl[l];
  float v = per * (1.0f / (4096.0f + 1e-5f));
  #pragma unroll
  for (int off = 1; off < 64; off <<= 1) v += __shfl_xor(v, off);
  __shared__ float wsum[4];
  if ((threadIdx.x & 63) == 0) wsum[threadIdx.x >> 6] = v;
  __syncthreads();
  if (threadIdx.x == 0)
    atomicAdd(out, wsum[0] + wsum[1] + wsum[2] + wsum[3]);
}

// ---------------------------------------------------------------- launch
extern "C" void kernel_launch(void* const* d_in, const int* in_sizes, int n_in,
                              void* d_out, int out_size, void* d_ws,
                              size_t ws_size, hipStream_t stream) {
  const float* hidden = (const float*)d_in[0];
  const int* begins = (const int*)d_in[1];
  const int* ends = (const int*)d_in[2];
  const int* bids = (const int*)d_in[3];
  const int* tags = (const int*)d_in[4];
  const float* W1 = (const float*)d_in[5];
  const float* b1 = (const float*)d_in[6];
  const float* W2 = (const float*)d_in[7];
  const float* b2 = (const float*)d_in[8];
  const float* Wo = (const float*)d_in[9];
  const float* bo = (const float*)d_in[10];
  float* out = (float*)d_out;

  ushort* featb = (ushort*)d_ws;                       // L*256
  ushort* Wob = featb + (size_t)L * 256;               // V*256
  ushort* spanb = Wob + (size_t)V * 256;               // L*1536
  ushort* W1b = spanb + (size_t)L * 1536;              // 256*1536
  ushort* W2b = W1b + (size_t)256 * 1536;              // 256*256
  // pz (NCH2*L f32 = 8 MB) aliases spanb (12.6 MB): spanb is dead after
  // feat_mfma_kernel, and logits2 runs strictly after it in-stream.
  float* pz = (float*)spanb;
  float* tagl = (float*)(W2b + (size_t)256 * 256);     // L

  hipMemsetAsync(d_out, 0, sizeof(float), stream);
  spanb_kernel<<<L / 2, 256, 0, stream>>>(hidden, begins, ends, bids, spanb);
  tcast_kernel<<<dim3(4, 24), 256, 0, stream>>>(W1, W1b, 1536, LAB);
  tcast_kernel<<<dim3(4, 4), 256, 0, stream>>>(W2, W2b, LAB, LAB);
  tcast_kernel<<<dim3(500, 4), 256, 0, stream>>>(Wo, Wob, LAB, V);
  feat_mfma_kernel<<<128, 256, 0, stream>>>(spanb, W1b, b1, W2b, b2, featb);
  logits2_kernel<<<dim3(16, NCH2), 256, 0, stream>>>(featb, Wob, bo, pz);
  tag_kernel<<<L / 4, 256, 0, stream>>>(featb, Wob, bo, tags, tagl);
  reduce_kernel<<<L / 256, 256, 0, stream>>>(pz, tagl, out);
}

// Round 3
// 290.379 us; speedup vs baseline: 1.4275x; 1.1861x over previous
//
#include <hip/hip_runtime.h>
#include <math.h>

#define S 2048
#define B 16
#define H 512
#define L 4096
#define SMAX 16
#define LAB 256
#define V 32000
#define NCH 250          // V / 128 vocab chunks
#define LOG2E 1.44269504f

typedef __attribute__((ext_vector_type(8))) short short8;
typedef __attribute__((ext_vector_type(4))) float float4v;

__device__ inline ushort f2bf(float x) {
  union { float f; unsigned u; } c; c.f = x;
  unsigned r = c.u + 0x7fffu + ((c.u >> 16) & 1u);
  return (ushort)(r >> 16);
}
__device__ inline float bf2f(ushort h) {
  union { unsigned u; float f; } c; c.u = ((unsigned)h) << 16;
  return c.f;
}

// ---------------------------------------------------------------- kernel A
// span gather -> spanb bf16 [L][1536] = concat(left, mean, right)
__global__ __launch_bounds__(256) void spanb_kernel(
    const float* __restrict__ hidden, const int* __restrict__ begins,
    const int* __restrict__ ends, const int* __restrict__ bids,
    ushort* __restrict__ spanb) {
  int sub = threadIdx.x >> 7, t = threadIdx.x & 127;
  int l = blockIdx.x * 2 + sub;
  int b = bids[l], s0 = begins[l], s1 = ends[l];
  const float4* hidv = (const float4*)hidden;
  float4 lf = hidv[((size_t)(s0 - 1) * B + b) * 128 + t];
  float4 rf = hidv[((size_t)s1 * B + b) * 128 + t];
  float4 m = make_float4(0.f, 0.f, 0.f, 0.f);
  int len = s1 - s0;
  for (int j = 0; j < len; ++j) {
    float4 g = hidv[((size_t)(s0 + j) * B + b) * 128 + t];
    m.x += g.x; m.y += g.y; m.z += g.z; m.w += g.w;
  }
  float inv = 1.0f / (float)len;
  ushort* sp = spanb + (size_t)l * 1536;
  ushort4 u;
  u.x = f2bf(lf.x); u.y = f2bf(lf.y); u.z = f2bf(lf.z); u.w = f2bf(lf.w);
  *(ushort4*)&sp[t * 4] = u;
  u.x = f2bf(m.x * inv); u.y = f2bf(m.y * inv);
  u.z = f2bf(m.z * inv); u.w = f2bf(m.w * inv);
  *(ushort4*)&sp[512 + t * 4] = u;
  u.x = f2bf(rf.x); u.y = f2bf(rf.y); u.z = f2bf(rf.z); u.w = f2bf(rf.w);
  *(ushort4*)&sp[1024 + t * 4] = u;
}

// ---------------------------------------------------------------- kernel B
// generic transpose+cast: src[K][N] f32 -> dst[N][K] bf16 (W1, W2)
__global__ __launch_bounds__(256) void tcast_kernel(
    const float* __restrict__ src, ushort* __restrict__ dst, int K, int N) {
  __shared__ ushort tile[64 * 72];
  int t = threadIdx.x;
  int n0 = blockIdx.x * 64;
  int k0 = blockIdx.y * 64;
  #pragma unroll
  for (int p = 0; p < 16; ++p) {
    int k = p * 4 + (t >> 6);
    int n = t & 63;
    tile[n * 72 + k] = f2bf(src[(size_t)(k0 + k) * N + n0 + n]);
  }
  __syncthreads();
  #pragma unroll
  for (int p = 0; p < 2; ++p) {
    int idx = p * 256 + t;
    int n = idx >> 3, c = idx & 7;
    *(uint4*)&dst[(size_t)(n0 + n) * K + k0 + c * 8] =
        *(const uint4*)&tile[n * 72 + c * 8];
  }
}

// ---------------------------------------------------------------- kernel B2
// Wo [256][32000] f32 -> fragment-major bf16 Wob:
//   frag f = (((c*2+kh)*4 + k4)*8 + nt)*64 + lq*16 + lr, 8 ushorts each,
//   where v = c*128 + nt*16 + lr, k = kh*128 + k4*32 + lq*8 + e.
// logits2 staging then becomes a pure linear 32KB copy (global_load_lds),
// and its ds_read_b128 fragment reads are 64 lanes x contiguous 16B
// (conflict-free; single addr reg + immediate offsets).
__global__ __launch_bounds__(256) void tcast_wo_kernel(
    const float* __restrict__ src, ushort* __restrict__ dst) {
  __shared__ ushort tile[64 * 72];
  int t = threadIdx.x;
  int n0 = blockIdx.x * 64;            // vocab
  int k0 = blockIdx.y * 64;            // K
  #pragma unroll
  for (int p = 0; p < 16; ++p) {
    int k = p * 4 + (t >> 6);
    int n = t & 63;
    tile[n * 72 + k] = f2bf(src[(size_t)(k0 + k) * V + n0 + n]);
  }
  __syncthreads();
  #pragma unroll
  for (int p = 0; p < 2; ++p) {
    int idx = p * 256 + t;             // 512 uint4 per tile
    int n = idx >> 3, c8 = idx & 7;
    int v = n0 + n, k = k0 + c8 * 8;
    int c = v >> 7, nt = (v >> 4) & 7, lr = v & 15;
    int kh = k >> 7, k4 = (k >> 5) & 3, lq = (k >> 3) & 3;
    size_t f = ((((size_t)c * 2 + kh) * 4 + k4) * 8 + nt) * 64 + lq * 16 + lr;
    *(uint4*)&dst[f * 8] = *(const uint4*)&tile[n * 72 + c8 * 8];
  }
}

// ---------------------------------------------------------------- kernel C
// MFMA MLP: featb = bf16( sigmoid(spanb@W1+b1) @ W2 + b2 )
#define FST 72
__global__ __launch_bounds__(256, 2) void feat_mfma_kernel(
    const ushort* __restrict__ spanb, const ushort* __restrict__ W1b,
    const float* __restrict__ b1, const ushort* __restrict__ W2b,
    const float* __restrict__ b2, ushort* __restrict__ featb) {
  __shared__ ushort As[32 * FST];
  __shared__ ushort Bs[256 * FST];
  __shared__ ushort Hs[32 * 264];
  int tid = threadIdx.x;
  int w = tid >> 6, lane = tid & 63;
  int lr = lane & 15, lq = lane >> 4;
  int l0 = blockIdx.x * 32;

  float4v acc[2][4];
  float4v zero = {0.f, 0.f, 0.f, 0.f};
  #pragma unroll
  for (int mt = 0; mt < 2; ++mt)
    #pragma unroll
    for (int nt = 0; nt < 4; ++nt) acc[mt][nt] = zero;

  for (int s = 0; s < 24; ++s) {
    int ks = s * 64;
    __syncthreads();
    {
      int r = tid >> 3, c = tid & 7;
      *(uint4*)&As[r * FST + c * 8] =
          *(const uint4*)&spanb[(size_t)(l0 + r) * 1536 + ks + c * 8];
    }
    #pragma unroll
    for (int p = 0; p < 8; ++p) {
      int idx = p * 256 + tid;
      int r = idx >> 3, c = idx & 7;
      *(uint4*)&Bs[r * FST + c * 8] =
          *(const uint4*)&W1b[(size_t)r * 1536 + ks + c * 8];
    }
    __syncthreads();
    #pragma unroll
    for (int kk = 0; kk < 2; ++kk) {
      short8 af[2], bf[4];
      #pragma unroll
      for (int mt = 0; mt < 2; ++mt)
        af[mt] = *(const short8*)&As[(mt * 16 + lr) * FST + kk * 32 + lq * 8];
      #pragma unroll
      for (int nt = 0; nt < 4; ++nt)
        bf[nt] = *(const short8*)
            &Bs[(w * 64 + nt * 16 + lr) * FST + kk * 32 + lq * 8];
      #pragma unroll
      for (int mt = 0; mt < 2; ++mt)
        #pragma unroll
        for (int nt = 0; nt < 4; ++nt)
          acc[mt][nt] = __builtin_amdgcn_mfma_f32_16x16x32_bf16(
              af[mt], bf[nt], acc[mt][nt], 0, 0, 0);
    }
  }

  {
    float b1v[4];
    #pragma unroll
    for (int nt = 0; nt < 4; ++nt) b1v[nt] = b1[w * 64 + nt * 16 + lr];
    #pragma unroll
    for (int mt = 0; mt < 2; ++mt)
      #pragma unroll
      for (int nt = 0; nt < 4; ++nt)
        #pragma unroll
        for (int r = 0; r < 4; ++r) {
          int row = mt * 16 + lq * 4 + r;
          int col = w * 64 + nt * 16 + lr;
          float h = 1.0f / (1.0f + __expf(-(acc[mt][nt][r] + b1v[nt])));
          Hs[row * 264 + col] = f2bf(h);
        }
  }

  float4v acc2[2][4];
  #pragma unroll
  for (int mt = 0; mt < 2; ++mt)
    #pragma unroll
    for (int nt = 0; nt < 4; ++nt) acc2[mt][nt] = zero;

  for (int s = 0; s < 4; ++s) {
    int ks = s * 64;
    __syncthreads();
    #pragma unroll
    for (int p = 0; p < 8; ++p) {
      int idx = p * 256 + tid;
      int r = idx >> 3, c = idx & 7;
      *(uint4*)&Bs[r * FST + c * 8] =
          *(const uint4*)&W2b[(size_t)r * 256 + ks + c * 8];
    }
    __syncthreads();
    #pragma unroll
    for (int kk = 0; kk < 2; ++kk) {
      short8 af[2], bf[4];
      #pragma unroll
      for (int mt = 0; mt < 2; ++mt)
        af[mt] = *(const short8*)
            &Hs[(mt * 16 + lr) * 264 + ks + kk * 32 + lq * 8];
      #pragma unroll
      for (int nt = 0; nt < 4; ++nt)
        bf[nt] = *(const short8*)
            &Bs[(w * 64 + nt * 16 + lr) * FST + kk * 32 + lq * 8];
      #pragma unroll
      for (int mt = 0; mt < 2; ++mt)
        #pragma unroll
        for (int nt = 0; nt < 4; ++nt)
          acc2[mt][nt] = __builtin_amdgcn_mfma_f32_16x16x32_bf16(
              af[mt], bf[nt], acc2[mt][nt], 0, 0, 0);
    }
  }

  {
    float b2v[4];
    #pragma unroll
    for (int nt = 0; nt < 4; ++nt) b2v[nt] = b2[w * 64 + nt * 16 + lr];
    #pragma unroll
    for (int mt = 0; mt < 2; ++mt)
      #pragma unroll
      for (int nt = 0; nt < 4; ++nt)
        #pragma unroll
        for (int r = 0; r < 4; ++r) {
          int row = mt * 16 + lq * 4 + r;
          int col = w * 64 + nt * 16 + lr;
          featb[(size_t)(l0 + row) * 256 + col] =
              f2bf(acc2[mt][nt][r] + b2v[nt]);
        }
  }
}

// ---------------------------------------------------------------- kernel D
// logits + sumexp partials. Round-0 co-schedule (x-fastest label blocks per
// chunk -> Wob chunk + featb slices L2-hot), rebalanced:
//  - wave tile 32 labels x 128 vocab (acc[2][8]): 16 MFMA per 2 A-loads
//    (round-2's acc[4][4] was 16 per 4 -> A-traffic halved per FLOP)
//  - chunk = 128 vocab rows, K staged in two 32KB halves -> LDS 32KB,
//    ~3 blocks/CU (regs ~144) vs round-0's 2
//  - Wob is fragment-major: staging = linear global_load_lds (async, no VGPR
//    round-trip); ds_read_b128 = 64 lanes x contiguous 16B, conflict-free
//    (round-2 paid exactly 4 extra cycles per read: 4.096M conflict cycles)
//  - s_setprio around MFMA cluster (phase-diverse blocks now co-resident)
__global__ __launch_bounds__(256, 3) void logits2_kernel(
    const ushort* __restrict__ featb, const ushort* __restrict__ Wob,
    const float* __restrict__ bo, float* __restrict__ pz) {
  __shared__ ushort Blds[16384];         // 32 KB: one K-half, fragment-major
  int tid = threadIdx.x;
  int w = tid >> 6, lane = tid & 63;
  int lr = lane & 15, lq = lane >> 4;
  int l0 = blockIdx.x * 128;
  int v0 = blockIdx.y * 128;

  // per-mt global A pointers; k-step advance = 32 ushorts = 4 short8
  const short8* aptr[2];
  #pragma unroll
  for (int mt = 0; mt < 2; ++mt)
    aptr[mt] = (const short8*)(featb +
        (size_t)(l0 + w * 32 + mt * 16 + lr) * 256 + lq * 8);

  float bov[8];
  #pragma unroll
  for (int nt = 0; nt < 8; ++nt)
    bov[nt] = bo[v0 + nt * 16 + lr] * LOG2E;

  float4v acc[2][8];
  float4v zero = {0.f, 0.f, 0.f, 0.f};
  #pragma unroll
  for (int mt = 0; mt < 2; ++mt)
    #pragma unroll
    for (int nt = 0; nt < 8; ++nt) acc[mt][nt] = zero;

  short8 af[2][2];
  #pragma unroll
  for (int mt = 0; mt < 2; ++mt) af[0][mt] = aptr[mt][0];

  #pragma unroll
  for (int kh = 0; kh < 2; ++kh) {
    // stage K-half kh: 2048 frags, pure linear copy, async to LDS
    {
      const uint4* src4 = (const uint4*)(Wob +
          (size_t)blockIdx.y * 32768 + (size_t)kh * 16384);
      #pragma unroll
      for (int p = 0; p < 8; ++p) {
        int idx = p * 256 + tid;
        __builtin_amdgcn_global_load_lds(
            (const __attribute__((address_space(1))) unsigned int*)(src4 + idx),
            (__attribute__((address_space(3))) unsigned int*)&Blds[(size_t)idx * 8],
            16, 0, 0);
      }
    }
    __syncthreads();                     // drains the LDS-DMA
    #pragma unroll
    for (int k4 = 0; k4 < 4; ++k4) {
      int kg = kh * 4 + k4;
      int cur = kg & 1, nxt = cur ^ 1;
      if (kg < 7) {
        #pragma unroll
        for (int mt = 0; mt < 2; ++mt)
          af[nxt][mt] = aptr[mt][(kg + 1) * 4];
      }
      short8 bf[8];
      #pragma unroll
      for (int nt = 0; nt < 8; ++nt)
        bf[nt] = *(const short8*)&Blds[(size_t)(((k4 * 8 + nt) * 64) + lane) * 8];
      __builtin_amdgcn_s_setprio(1);
      #pragma unroll
      for (int mt = 0; mt < 2; ++mt)
        #pragma unroll
        for (int nt = 0; nt < 8; ++nt)
          acc[mt][nt] = __builtin_amdgcn_mfma_f32_16x16x32_bf16(
              af[cur][mt], bf[nt], acc[mt][nt], 0, 0, 0);
      __builtin_amdgcn_s_setprio(0);
    }
    if (kh == 0) __syncthreads();        // protect Blds before restage
  }

  // epilogue: z[row] = sum_cols exp(logit + bo), no max (logits bounded)
  float z[2][4];
  #pragma unroll
  for (int mt = 0; mt < 2; ++mt)
    #pragma unroll
    for (int r = 0; r < 4; ++r) z[mt][r] = 0.f;
  #pragma unroll
  for (int mt = 0; mt < 2; ++mt)
    #pragma unroll
    for (int nt = 0; nt < 8; ++nt)
      #pragma unroll
      for (int r = 0; r < 4; ++r)
        z[mt][r] += exp2f(fmaf(acc[mt][nt][r], LOG2E, bov[nt]));
  #pragma unroll
  for (int mt = 0; mt < 2; ++mt)
    #pragma unroll
    for (int r = 0; r < 4; ++r) {
      #pragma unroll
      for (int off = 1; off < 16; off <<= 1)
        z[mt][r] += __shfl_xor(z[mt][r], off);
    }
  if (lr == 0) {
    int ch = blockIdx.y;
    #pragma unroll
    for (int mt = 0; mt < 2; ++mt) {
      float4 v4;
      v4.x = z[mt][0]; v4.y = z[mt][1]; v4.z = z[mt][2]; v4.w = z[mt][3];
      *(float4*)&pz[(size_t)ch * L + l0 + w * 32 + mt * 16 + lq * 4] = v4;
    }
  }
}

// ---------------------------------------------------------------- kernel E
// Exact tag logit from fragment-major Wob (same bf16 values as pz path).
// lane handles k0 = lane*4: one ushort4 of W (within one fragment, e in {0,4})
__global__ __launch_bounds__(256) void tag_kernel(
    const ushort* __restrict__ featb, const ushort* __restrict__ Wob,
    const float* __restrict__ bo, const int* __restrict__ tags,
    float* __restrict__ tagl) {
  int l = blockIdx.x * 4 + (threadIdx.x >> 6);
  int lane = threadIdx.x & 63;
  int tg = tags[l];
  int c = tg >> 7, nt = (tg >> 4) & 7, lr = tg & 15;
  int k0 = lane << 2;
  int kh = k0 >> 7, k4 = (k0 >> 5) & 3, lq = (k0 >> 3) & 3, e = k0 & 7;
  size_t f = ((((size_t)c * 2 + kh) * 4 + k4) * 8 + nt) * 64 + lq * 16 + lr;
  ushort4 wa = *(const ushort4*)&Wob[f * 8 + e];
  ushort4 fa = *(const ushort4*)&featb[(size_t)l * 256 + k0];
  float s = bf2f(fa.x) * bf2f(wa.x) + bf2f(fa.y) * bf2f(wa.y) +
            bf2f(fa.z) * bf2f(wa.z) + bf2f(fa.w) * bf2f(wa.w);
  #pragma unroll
  for (int off = 1; off < 64; off <<= 1) s += __shfl_xor(s, off);
  if (lane == 0) tagl[l] = s + bo[tg];
}

// ---------------------------------------------------------------- kernel F
__global__ __launch_bounds__(256) void reduce_kernel(
    const float* __restrict__ pz, const float* __restrict__ tagl,
    float* __restrict__ out) {
  int l = blockIdx.x * 256 + threadIdx.x;
  float z = 0.f;
  for (int c = 0; c < NCH; ++c) z += pz[(size_t)c * L + l];
  float per = logf(z) - tagl[l];
  float v = per * (1.0f / (4096.0f + 1e-5f));
  #pragma unroll
  for (int off = 1; off < 64; off <<= 1) v += __shfl_xor(v, off);
  __shared__ float wsum[4];
  if ((threadIdx.x & 63) == 0) wsum[threadIdx.x >> 6] = v;
  __syncthreads();
  if (threadIdx.x == 0)
    atomicAdd(out, wsum[0] + wsum[1] + wsum[2] + wsum[3]);
}

// ---------------------------------------------------------------- launch
extern "C" void kernel_launch(void* const* d_in, const int* in_sizes, int n_in,
                              void* d_out, int out_size, void* d_ws,
                              size_t ws_size, hipStream_t stream) {
  const float* hidden = (const float*)d_in[0];
  const int* begins = (const int*)d_in[1];
  const int* ends = (const int*)d_in[2];
  const int* bids = (const int*)d_in[3];
  const int* tags = (const int*)d_in[4];
  const float* W1 = (const float*)d_in[5];
  const float* b1 = (const float*)d_in[6];
  const float* W2 = (const float*)d_in[7];
  const float* b2 = (const float*)d_in[8];
  const float* Wo = (const float*)d_in[9];
  const float* bo = (const float*)d_in[10];
  float* out = (float*)d_out;

  ushort* featb = (ushort*)d_ws;                       // L*256
  ushort* Wob = featb + (size_t)L * 256;               // V*256 (frag-major)
  ushort* spanb = Wob + (size_t)V * 256;               // L*1536
  ushort* W1b = spanb + (size_t)L * 1536;              // 256*1536
  ushort* W2b = W1b + (size_t)256 * 1536;              // 256*256
  // pz (NCH*L f32 = 4.1 MB) aliases spanb (12.6 MB): spanb dead after
  // feat_mfma_kernel; logits2 runs strictly after it in-stream.
  float* pz = (float*)spanb;
  float* tagl = (float*)(W2b + (size_t)256 * 256);     // L

  hipMemsetAsync(d_out, 0, sizeof(float), stream);
  spanb_kernel<<<L / 2, 256, 0, stream>>>(hidden, begins, ends, bids, spanb);
  tcast_kernel<<<dim3(4, 24), 256, 0, stream>>>(W1, W1b, 1536, LAB);
  tcast_kernel<<<dim3(4, 4), 256, 0, stream>>>(W2, W2b, LAB, LAB);
  tcast_wo_kernel<<<dim3(500, 4), 256, 0, stream>>>(Wo, Wob);
  feat_mfma_kernel<<<128, 256, 0, stream>>>(spanb, W1b, b1, W2b, b2, featb);
  logits2_kernel<<<dim3(32, NCH), 256, 0, stream>>>(featb, Wob, bo, pz);
  tag_kernel<<<L / 4, 256, 0, stream>>>(featb, Wob, bo, tags, tagl);
  reduce_kernel<<<L / 256, 256, 0, stream>>>(pz, tagl, out);
}